// Round 15
// baseline (61536.639 us; speedup 1.0000x reference)
//
#include <hip/hip_runtime.h>

// Echo-state network recurrence on MI355X (gfx950).
// Round-27: CHUNK-PIPELINED DIRECT POLL. r26 measured: poll phase ~690cyc
// (sleep128 + ~1 failed + 1 success round -> commit latency 150-400cyc,
// detect commit-bound; explains r24/r25 nulls). Non-poll ~1330cyc, of
// which only ~650 is instructions -> ~600cyc is the barrier absorbing
// co-wave straggle: the 4 quarters are fed by ALL 32 blocks, so every
// step waits on the full-team max commit doing NOTHING (r25's all-tags
// check had the same property). Fix: r23's concept, r25's skeleton --
// issue all 4 chunk loads, check freshness PER CHUNK, reissue stale
// chunks FIRST (flight overlaps compute), then FMA fresh chunks.
// Straggler re-poll RTT hides under FMA of arrived chunks. Chunks FMA
// in arrival order -> summation reassociation only (~1e-6, far below
// the 2^-16 pack noise; threshold 0.69, we sit at 0.125). All branches
// __all-uniform. Stage/barrier/ds_read deleted (r25: free). Placement
// force (96KiB LDS, r22) retained. LEDGER r26: one wave's s_memtime
// slows the whole team via lockstep (+4.4ms) -- probes removed.

#define HH    1024
#define TT    50000
#define WASH  200
#define NBROLE 32   // block role b; wave ww -> global role 4b+ww, rows [8role, 8role+8)
#define NBLK  512
#define NT    256
#define SPIN_CAP (1u << 20)
#define LDSPAD 98304   // 96 KiB total LDS -> 1 block/CU (LDS pool 160 KiB)

typedef unsigned int u32;
typedef u32 u32x4 __attribute__((ext_vector_type(4)));
typedef float f32x4 __attribute__((ext_vector_type(4)));
typedef float f32x2 __attribute__((ext_vector_type(2)));

__device__ __forceinline__ float fast_tanh(float x) {
  // tanh(x) = 1 - 2/(exp2(2x*log2e)+1); safe at +/-inf.
  float e = __builtin_amdgcn_exp2f(x * 2.8853900817779268f);
  return fmaf(-2.0f, __builtin_amdgcn_rcpf(e + 1.0f), 1.0f);
}

template <int CTRL>
__device__ __forceinline__ float dpp_movf(float x) {
  return __int_as_float(__builtin_amdgcn_update_dpp(
      0, __float_as_int(x), CTRL, 0xF, 0xF, true));
}
__device__ __forceinline__ float swz_xor16(float x) {
  return __int_as_float(__builtin_amdgcn_ds_swizzle(__float_as_int(x), 0x401F));
}

#define YREDUCE()                                                         \
  { y += __shfl_xor(y, 32);                                               \
    y += swz_xor16(y);                                                    \
    y += dpp_movf<0x128>(y);   /* row_ror:8   */                          \
    y += dpp_movf<0x141>(y);   /* half mirror */                          \
    y += dpp_movf<0x1B>(y);    /* quad reverse*/                          \
    y += dpp_movf<0xB1>(y); }  /* quad xor1   */

// chunk loads: chunk k covers cols 256k+4l..+3 (pairs 2k, 2k+1)
#define ISS0() asm volatile("global_load_dwordx4 %0, %1, off sc1"             : "=v"(p0) : "v"(src))
#define ISS1() asm volatile("global_load_dwordx4 %0, %1, off offset:1024 sc1" : "=v"(p1) : "v"(src))
#define ISS2() asm volatile("global_load_dwordx4 %0, %1, off offset:2048 sc1" : "=v"(p2) : "v"(src))
#define ISS3() asm volatile("global_load_dwordx4 %0, %1, off offset:3072 sc1" : "=v"(p3) : "v"(src))
#define WAIT_ALL()                                                        \
  asm volatile("s_waitcnt vmcnt(0)"                                       \
               : "+v"(p0), "+v"(p1), "+v"(p2), "+v"(p3))

// FULL per-dword tag check (partial-commit visibility: load-bearing).
#define TAGBAD(q) ((((q.x ^ want) | (q.y ^ want) | (q.z ^ want) | (q.w ^ want)) & 0xFFu))
#define FRESH(q) (__all(TAGBAD(q) == 0u))

// unpack one 16B chunk into two f32x2 value pairs (pair b2, b2+1)
#define UNPACK2(q, b2)                                                    \
  { xv2[b2+0] = (f32x2){__uint_as_float(q.x & 0xFFFFFF00u),               \
                        __uint_as_float(q.y & 0xFFFFFF00u)};              \
    xv2[b2+1] = (f32x2){__uint_as_float(q.z & 0xFFFFFF00u),               \
                        __uint_as_float(q.w & 0xFFFFFF00u)}; }

// --- named weight registers: row r, pairs 0..7 (cols 256*(p>>1)+4l+{2(p&1),+1})
#define DECLW(r) f32x2 W##r##0, W##r##1, W##r##2, W##r##3,                \
                      W##r##4, W##r##5, W##r##6, W##r##7

#define LOADW(r) do {                                                     \
  const float* wp = w_res + (size_t)(32 * b + 8 * ww + r) * HH + 4 * l;   \
  f32x4 va = *(const f32x4*)(wp);                                         \
  f32x4 vb = *(const f32x4*)(wp + 256);                                   \
  f32x4 vc = *(const f32x4*)(wp + 512);                                   \
  f32x4 vd = *(const f32x4*)(wp + 768);                                   \
  W##r##0 = (f32x2){va.x, va.y}; W##r##1 = (f32x2){va.z, va.w};           \
  W##r##2 = (f32x2){vb.x, vb.y}; W##r##3 = (f32x2){vb.z, vb.w};           \
  W##r##4 = (f32x2){vc.x, vc.y}; W##r##5 = (f32x2){vc.z, vc.w};           \
  W##r##6 = (f32x2){vd.x, vd.y}; W##r##7 = (f32x2){vd.z, vd.w};           \
} while (0)

// one chunk's 16 pk-FMAs (pairs pA=2k, pB=2k+1, all 8 rows)
#define FMA_CHUNK(pA, pB)                                                 \
  acc2[0] = __builtin_elementwise_fma(W0##pA, xv2[pA], acc2[0]);          \
  acc2[0] = __builtin_elementwise_fma(W0##pB, xv2[pB], acc2[0]);          \
  acc2[1] = __builtin_elementwise_fma(W1##pA, xv2[pA], acc2[1]);          \
  acc2[1] = __builtin_elementwise_fma(W1##pB, xv2[pB], acc2[1]);          \
  acc2[2] = __builtin_elementwise_fma(W2##pA, xv2[pA], acc2[2]);          \
  acc2[2] = __builtin_elementwise_fma(W2##pB, xv2[pB], acc2[2]);          \
  acc2[3] = __builtin_elementwise_fma(W3##pA, xv2[pA], acc2[3]);          \
  acc2[3] = __builtin_elementwise_fma(W3##pB, xv2[pB], acc2[3]);          \
  acc2[4] = __builtin_elementwise_fma(W4##pA, xv2[pA], acc2[4]);          \
  acc2[4] = __builtin_elementwise_fma(W4##pB, xv2[pB], acc2[4]);          \
  acc2[5] = __builtin_elementwise_fma(W5##pA, xv2[pA], acc2[5]);          \
  acc2[5] = __builtin_elementwise_fma(W5##pB, xv2[pB], acc2[5]);          \
  acc2[6] = __builtin_elementwise_fma(W6##pA, xv2[pA], acc2[6]);          \
  acc2[6] = __builtin_elementwise_fma(W6##pB, xv2[pB], acc2[6]);          \
  acc2[7] = __builtin_elementwise_fma(W7##pA, xv2[pA], acc2[7]);          \
  acc2[7] = __builtin_elementwise_fma(W7##pB, xv2[pB], acc2[7]);

__global__ __launch_bounds__(NT, 1) void esn_kernel(
    const float* __restrict__ u,
    const float* __restrict__ w_in,
    const float* __restrict__ w_res,
    const float* __restrict__ w_out,
    const int*   __restrict__ mask,
    float*       __restrict__ out,
    char*        __restrict__ ws)
{
  const int tid = threadIdx.x;
  const int l  = tid & 63;     // lane within wave
  const int ww = tid >> 6;     // wave id within block (0..3)

  // --- team formation: XCD 0 only, first 32 claimant BLOCKS persist ---
  u32 xcc;
  asm("s_getreg_b32 %0, hwreg(HW_REG_XCC_ID)" : "=s"(xcc));
  if (xcc != 0) return;        // uniform per block (block lives on one CU)

  // PLACEMENT FORCE (r22-proven): 96 KiB static LDS -> 1 block/CU ->
  // the 32 claim winners sit on 32 distinct CUs.
  __shared__ __align__(16) char lds_all[LDSPAD];
  float* lds_c = (float*)lds_all;                        // 4 KB coeffs
  int* slot_p = (int*)(lds_all + 4096);

  if (tid == 0) *slot_p = atomicAdd((int*)ws, 1);  // ws[0..63] zeroed each launch
  // init readout coeffs while the claim settles
  for (int h = tid; h < HH; h += NT) lds_c[mask[h]] = w_out[h];
  __syncthreads();
  const int b = *slot_p;
  if (b >= NBROLE) return;

  u32* xb0 = (u32*)(ws + 4096);        // parity-0 packed buffer (4 KB)
  u32* xb1 = xb0 + HH;                 // parity-1 packed buffer (4 KB)

  // weights: 8 rows x 8 col-pairs per lane (rows 32b+8ww .. +8)
  DECLW(0); DECLW(1); DECLW(2); DECLW(3);
  DECLW(4); DECLW(5); DECLW(6); DECLW(7);
  LOADW(0); LOADW(1); LOADW(2); LOADW(3);
  LOADW(4); LOADW(5); LOADW(6); LOADW(7);

  const float win = w_in[32 * b + 8 * ww + (l >> 3)];

  f32x2 cr2[8];                        // readout coeffs, same col map
#pragma unroll
  for (int k = 0; k < 4; ++k) {
    f32x4 v = *(const f32x4*)(lds_c + 256 * k + 4 * l);
    cr2[2*k+0] = (f32x2){v.x, v.y};
    cr2[2*k+1] = (f32x2){v.z, v.w};
  }

  // full-state poll pointers (per lane: 4 chunks at +0/+1024/+2048/+3072 B)
  const u32* pA0 = xb0 + 4 * l;
  const u32* pA1 = xb1 + 4 * l;
  // publish pointers: lane (l&7)==0 stores row 32b+8ww+(l>>3)
  const int drow = 32 * b + 8 * ww + (l >> 3);
  u32* d0 = xb0 + drow;
  u32* d1 = xb1 + drow;

  const int role = (b << 2) | ww;      // 0..127, readout rotation
  u32x4 p0, p1, p2, p3;
  const int lb32 = l & 32, lb16 = l & 16, lb8 = l & 8;
  int dead = 0;

  for (int t = 0; t < TT; ++t) {
    const int pa = t & 1;
    const float u_t = u[t];
    f32x2 acc2[8];
#pragma unroll
    for (int i = 0; i < 8; ++i) acc2[i] = (f32x2){0.f, 0.f};
    f32x2 xv2[8];
    const bool doRead = ((t & 127) == role) && (t > 0);

    if (t > 0 && !dead) {
      // delayed first poll covers most of store-commit; after that the
      // chunk pipeline handles stragglers.
      __builtin_amdgcn_s_sleep(2);
      const u32* src = pa ? pA0 : pA1;   // source = buf[(t-1)&1]
      const u32 want = (u32)t & 0xFFu;   // generation of x_{t-1}
      ISS0(); ISS1(); ISS2(); ISS3();
      WAIT_ALL();
      bool f0 = FRESH(p0), f1 = FRESH(p1), f2 = FRESH(p2), f3 = FRESH(p3);
      bool e0 = false, e1 = false, e2 = false, e3 = false;  // FMA'd?
      u32 guard = 0;
      for (;;) {
        // 1) reissue stale chunks FIRST -- their RTT flies under the FMAs
        if (!f0) ISS0();
        if (!f1) ISS1();
        if (!f2) ISS2();
        if (!f3) ISS3();
        // 2) FMA fresh, not-yet-consumed chunks (arrival order; uniform)
        if (f0 && !e0) { UNPACK2(p0, 0); FMA_CHUNK(0, 1); e0 = true; }
        if (f1 && !e1) { UNPACK2(p1, 2); FMA_CHUNK(2, 3); e1 = true; }
        if (f2 && !e2) { UNPACK2(p2, 4); FMA_CHUNK(4, 5); e2 = true; }
        if (f3 && !e3) { UNPACK2(p3, 6); FMA_CHUNK(6, 7); e3 = true; }
        if (e0 && e1 && e2 && e3) break;
        WAIT_ALL();
        if (!f0) f0 = FRESH(p0);
        if (!f1) f1 = FRESH(p1);
        if (!f2) f2 = FRESH(p2);
        if (!f3) f3 = FRESH(p3);
        if (++guard > SPIN_CAP) { dead = 1; break; }
      }
    }

    // horizontal pair-sum, then fold 64 lanes x 8 accs -> row (l>>3) sum
    // on lanes with (l&7)==0
    const float a0 = acc2[0].x + acc2[0].y, a1 = acc2[1].x + acc2[1].y;
    const float a2 = acc2[2].x + acc2[2].y, a3 = acc2[3].x + acc2[3].y;
    const float a4 = acc2[4].x + acc2[4].y, a5 = acc2[5].x + acc2[5].y;
    const float a6 = acc2[6].x + acc2[6].y, a7 = acc2[7].x + acc2[7].y;
    float t0 = (lb32 ? a4 : a0) + __shfl_xor(lb32 ? a0 : a4, 32);
    float t1 = (lb32 ? a5 : a1) + __shfl_xor(lb32 ? a1 : a5, 32);
    float t2 = (lb32 ? a6 : a2) + __shfl_xor(lb32 ? a2 : a6, 32);
    float t3 = (lb32 ? a7 : a3) + __shfl_xor(lb32 ? a3 : a7, 32);
    float s0 = (lb16 ? t2 : t0) + swz_xor16(lb16 ? t0 : t2);
    float s1 = (lb16 ? t3 : t1) + swz_xor16(lb16 ? t1 : t3);
    float r0 = (lb8 ? s1 : s0) + dpp_movf<0x128>(lb8 ? s0 : s1);
    r0 += dpp_movf<0x141>(r0);
    r0 += dpp_movf<0x1B>(r0);
    r0 += dpp_movf<0xB1>(r0);

    float x_new = fast_tanh(fmaf(win, u_t, r0));
    // pack: RN-round mantissa to 15 bits, fuse generation tag (t+1)&0xFF
    u32 packed = ((__float_as_uint(x_new) + 0x80u) & 0xFFFFFF00u)
               | ((u32)(t + 1) & 0xFFu);
    if ((l & 7) == 0) {
      u32* dst = pa ? d1 : d0;          // x_t -> buf[t&1]
      // PLAIN store: write-through L1 -> dirty in XCD0's shared L2
      // (r9-proven; r16 proved atomics force the exchange out of L2).
      asm volatile("global_store_dword %0, %1, off" :: "v"(dst), "v"(packed));
    }

    // readout y_{t-1} from this step's unpacked values (off critical path)
    if (doRead) {
      f32x2 y2 = (f32x2){0.f, 0.f};
#pragma unroll
      for (int jj = 0; jj < 8; ++jj)
        y2 = __builtin_elementwise_fma(cr2[jj], xv2[jj], y2);
      float y = y2.x + y2.y;
      YREDUCE();
      if (l == 0 && t - 1 >= WASH) out[t - 1 - WASH] = y;
    }
  }

  // final readout: x_{TT-1} (tag TT) in buf[1]; role 0 polls directly.
  if (b == 0 && ww == 0) {
    const u32 want = (u32)TT & 0xFFu;
    const u32* src = pA1;
    u32 guard = 0;
    for (;;) {
      ISS0(); ISS1(); ISS2(); ISS3();
      WAIT_ALL();
      if (FRESH(p0) && FRESH(p1) && FRESH(p2) && FRESH(p3)) break;
      if (++guard > SPIN_CAP) break;
    }
    f32x2 xv2[8];
    UNPACK2(p0, 0); UNPACK2(p1, 2); UNPACK2(p2, 4); UNPACK2(p3, 6);
    f32x2 y2 = (f32x2){0.f, 0.f};
#pragma unroll
    for (int jj = 0; jj < 8; ++jj)
      y2 = __builtin_elementwise_fma(cr2[jj], xv2[jj], y2);
    float y = y2.x + y2.y;
    YREDUCE();
    if (l == 0) out[TT - 1 - WASH] = y;
  }
}

extern "C" void kernel_launch(void* const* d_in, const int* in_sizes, int n_in,
                              void* d_out, int out_size, void* d_ws, size_t ws_size,
                              hipStream_t stream) {
  const float* u     = (const float*)d_in[0];
  const float* w_in  = (const float*)d_in[1];
  const float* w_res = (const float*)d_in[2];
  const float* w_out = (const float*)d_in[3];
  const int*   mask  = (const int*)d_in[4];
  float* out = (float*)d_out;

  // zero the block-claim counter; packed buffers rely on 0xAA poison
  // (tag byte 0xAA only ever compared against want in {1,2})
  hipMemsetAsync(d_ws, 0, 64, stream);

  esn_kernel<<<NBLK, NT, 0, stream>>>(u, w_in, w_res, w_out, mask, out,
                                      (char*)d_ws);
}

// Round 16
// 46624.838 us; speedup vs baseline: 1.3198x; 1.3198x over previous
//
#include <hip/hip_runtime.h>

// Echo-state network recurrence on MI355X (gfx950).
// Round-28: r22 EXACT + SLEEP RETUNE (single knob). r27 (chunk pipeline)
// regressed 42.1->61.5ms: per-iteration vmcnt(0) waits serialize the
// reissued stragglers' RTT (only ~64cyc FMA hidden), 4x traffic, branchy
// body. LEDGER: overlap gated on vmcnt(0) serializes what it hides;
// barrier+bulk-LDS exchange beats flags/direct/chunk (3rd confirmation).
// r26 measured poll ~690cyc = sleep(128) + ~2 rounds: the FIRST poll
// reads L2 at ~250cyc, BEFORE the producer's commit (~300+cyc) -> one
// guaranteed-failed round. Serial-poll quantization: mistimed first read
// costs a full RTT. Fix: sleep(2)->sleep(4) (128->256cyc) so the first
// read lands just after the typical commit -> detection ~sleep+RTT~510
// vs 690, ~150-180cyc/step ~= 3ms. Zero added traffic (removes one
// failed 128KB team-wide poll round per step). Datapath untouched.

#define HH    1024
#define TT    50000
#define WASH  200
#define NBROLE 32   // block role b owns rows [32b, 32b+32); wave ww rows [32b+8ww, +8)
#define NBLK  512
#define NT    256
#define SPIN_CAP (1u << 20)
#define LDSPAD 98304   // 96 KiB total LDS -> 1 block/CU (LDS pool 160 KiB)

typedef unsigned int u32;
typedef u32 u32x4 __attribute__((ext_vector_type(4)));
typedef float f32x4 __attribute__((ext_vector_type(4)));
typedef float f32x2 __attribute__((ext_vector_type(2)));

__device__ __forceinline__ float fast_tanh(float x) {
  // tanh(x) = 1 - 2/(exp2(2x*log2e)+1); safe at +/-inf.
  float e = __builtin_amdgcn_exp2f(x * 2.8853900817779268f);
  return fmaf(-2.0f, __builtin_amdgcn_rcpf(e + 1.0f), 1.0f);
}

template <int CTRL>
__device__ __forceinline__ float dpp_movf(float x) {
  return __int_as_float(__builtin_amdgcn_update_dpp(
      0, __float_as_int(x), CTRL, 0xF, 0xF, true));
}
__device__ __forceinline__ float swz_xor16(float x) {
  return __int_as_float(__builtin_amdgcn_ds_swizzle(__float_as_int(x), 0x401F));
}

#define YREDUCE()                                                         \
  { y += __shfl_xor(y, 32);                                               \
    y += swz_xor16(y);                                                    \
    y += dpp_movf<0x128>(y);   /* row_ror:8   */                          \
    y += dpp_movf<0x141>(y);   /* half mirror */                          \
    y += dpp_movf<0x1B>(y);    /* quad reverse*/                          \
    y += dpp_movf<0xB1>(y); }  /* quad xor1   */

// single 16B poll load: own quarter only (lane l -> cols 256*ww + 4l .. +3)
#define POLL_ISSUE1(b)                                                    \
  asm volatile("global_load_dwordx4 %0, %1, off sc1" : "=v"(p) : "v"(b))
#define POLL_WAIT1()                                                      \
  asm volatile("s_waitcnt vmcnt(0)" : "+v"(p))

// FULL 4-dword tag check -- load-bearing (partial-commit visibility of
// coalesced wave stores means every dword's tag matters).
#define TAGBAD(q) ((((q.x ^ want) | (q.y ^ want) | (q.z ^ want) | (q.w ^ want)) & 0xFFu))

// unpack one 16B chunk into two f32x2 value pairs (pair b2, b2+1)
#define UNPACK2(q, b2)                                                    \
  { xv2[b2+0] = (f32x2){__uint_as_float(q.x & 0xFFFFFF00u),               \
                        __uint_as_float(q.y & 0xFFFFFF00u)};              \
    xv2[b2+1] = (f32x2){__uint_as_float(q.z & 0xFFFFFF00u),               \
                        __uint_as_float(q.w & 0xFFFFFF00u)}; }

// --- named weight registers: row r, pairs 0..7 (cols 256*(p>>1)+4l+{2(p&1),+1})
#define DECLW(r) f32x2 W##r##0, W##r##1, W##r##2, W##r##3,                \
                      W##r##4, W##r##5, W##r##6, W##r##7

#define LOADW(r) do {                                                     \
  const float* wp = w_res + (size_t)(32 * b + 8 * ww + r) * HH + 4 * l;   \
  f32x4 va = *(const f32x4*)(wp);                                         \
  f32x4 vb = *(const f32x4*)(wp + 256);                                   \
  f32x4 vc = *(const f32x4*)(wp + 512);                                   \
  f32x4 vd = *(const f32x4*)(wp + 768);                                   \
  W##r##0 = (f32x2){va.x, va.y}; W##r##1 = (f32x2){va.z, va.w};           \
  W##r##2 = (f32x2){vb.x, vb.y}; W##r##3 = (f32x2){vb.z, vb.w};           \
  W##r##4 = (f32x2){vc.x, vc.y}; W##r##5 = (f32x2){vc.z, vc.w};           \
  W##r##6 = (f32x2){vd.x, vd.y}; W##r##7 = (f32x2){vd.z, vd.w};           \
} while (0)

// jj ascending per accumulator -> identical summation order to r13-r27
#define FMAR(r) do {                                                      \
  acc2[r] = __builtin_elementwise_fma(W##r##0, xv2[0], acc2[r]);          \
  acc2[r] = __builtin_elementwise_fma(W##r##1, xv2[1], acc2[r]);          \
  acc2[r] = __builtin_elementwise_fma(W##r##2, xv2[2], acc2[r]);          \
  acc2[r] = __builtin_elementwise_fma(W##r##3, xv2[3], acc2[r]);          \
  acc2[r] = __builtin_elementwise_fma(W##r##4, xv2[4], acc2[r]);          \
  acc2[r] = __builtin_elementwise_fma(W##r##5, xv2[5], acc2[r]);          \
  acc2[r] = __builtin_elementwise_fma(W##r##6, xv2[6], acc2[r]);          \
  acc2[r] = __builtin_elementwise_fma(W##r##7, xv2[7], acc2[r]);          \
} while (0)

__global__ __launch_bounds__(NT, 1) void esn_kernel(
    const float* __restrict__ u,
    const float* __restrict__ w_in,
    const float* __restrict__ w_res,
    const float* __restrict__ w_out,
    const int*   __restrict__ mask,
    float*       __restrict__ out,
    char*        __restrict__ ws)
{
  const int tid = threadIdx.x;
  const int l  = tid & 63;     // lane within wave
  const int ww = tid >> 6;     // wave id within block (0..3) = quarter owner

  // --- team formation: XCD 0 only, first 32 claimant BLOCKS persist ---
  u32 xcc;
  asm("s_getreg_b32 %0, hwreg(HW_REG_XCC_ID)" : "=s"(xcc));
  if (xcc != 0) return;        // uniform per block (block lives on one CU)

  // PLACEMENT FORCE (r22-proven): 96 KiB static LDS -> 1 block/CU ->
  // the 32 claim winners sit on 32 distinct CUs.
  __shared__ __align__(16) char lds_all[LDSPAD];
  float* lds_c = (float*)lds_all;                        // 4 KB coeffs
  u32 (*lds_x)[HH] = (u32 (*)[HH])(lds_all + 4096);      // 2x4 KB state
  int* slot_p = (int*)(lds_all + 4096 + 8192);

  if (tid == 0) *slot_p = atomicAdd((int*)ws, 1);  // ws[0..63] zeroed each launch
  // init readout coeffs while the claim settles
  for (int h = tid; h < HH; h += NT) lds_c[mask[h]] = w_out[h];
  __syncthreads();
  const int b = *slot_p;
  if (b >= NBROLE) return;

  u32* xb0 = (u32*)(ws + 4096);        // parity-0 packed buffer (4 KB)
  u32* xb1 = xb0 + HH;                 // parity-1 packed buffer (4 KB)

  // weights: 8 rows x 8 col-pairs per lane (rows 32b+8ww .. +8)
  DECLW(0); DECLW(1); DECLW(2); DECLW(3);
  DECLW(4); DECLW(5); DECLW(6); DECLW(7);
  LOADW(0); LOADW(1); LOADW(2); LOADW(3);
  LOADW(4); LOADW(5); LOADW(6); LOADW(7);

  const float win = w_in[32 * b + 8 * ww + (l >> 3)];

  f32x2 cr2[8];                        // readout coeffs, same col map
#pragma unroll
  for (int k = 0; k < 4; ++k) {
    f32x4 v = *(const f32x4*)(lds_c + 256 * k + 4 * l);
    cr2[2*k+0] = (f32x2){v.x, v.y};
    cr2[2*k+1] = (f32x2){v.z, v.w};
  }

  // own-quarter poll pointers: wave ww covers cols [256ww, 256ww+256)
  const u32* pS0 = xb0 + 256 * ww + 4 * l;
  const u32* pS1 = xb1 + 256 * ww + 4 * l;
  // publish pointers: lane (l&7)==0 stores row 32b+8ww+(l>>3)
  const int drow = 32 * b + 8 * ww + (l >> 3);
  u32* d0 = xb0 + drow;
  u32* d1 = xb1 + drow;
  // LDS staging address (own quarter)
  const int stg = 256 * ww + 4 * l;

  const int role = (b << 2) | ww;      // 0..127, readout rotation
  u32x4 p;
  const int lb32 = l & 32, lb16 = l & 16, lb8 = l & 8;
  int dead = 0;

  for (int t = 0; t < TT; ++t) {
    const int pa = t & 1;
    const float u_t = u[t];
    f32x2 acc2[8];
#pragma unroll
    for (int i = 0; i < 8; ++i) acc2[i] = (f32x2){0.f, 0.f};
    f32x2 xv2[8];
    const bool doRead = ((t & 127) == role) && (t > 0);

    if (t > 0) {
      const int h = pa ^ 1;            // source parity = (t-1)&1
      if (!dead) {
        // RETUNED delayed first poll: sleep(4)=256cyc puts the first
        // L2 read just after the typical store-commit point (r26:
        // sleep(2) left the first round reading pre-commit -> one
        // guaranteed-failed round, a full wasted RTT).
        __builtin_amdgcn_s_sleep(4);
        const u32* src = h ? pS1 : pS0;
        const u32 want = (u32)t & 0xFFu;   // generation of x_{t-1}
        u32 guard = 0;
        for (;;) {
          POLL_ISSUE1(src);
          POLL_WAIT1();
          if (!TAGBAD(p)) break;
          if (++guard > SPIN_CAP) { dead = 1; break; }
        }
      }
      // stage own quarter to LDS; barrier; read full state from LDS
      *(u32x4*)(&lds_x[h][stg]) = p;
      __syncthreads();
      u32x4 c0 = *(const u32x4*)(&lds_x[h][  0 + 4 * l]);
      u32x4 c1 = *(const u32x4*)(&lds_x[h][256 + 4 * l]);
      u32x4 c2 = *(const u32x4*)(&lds_x[h][512 + 4 * l]);
      u32x4 c3 = *(const u32x4*)(&lds_x[h][768 + 4 * l]);
      UNPACK2(c0, 0); UNPACK2(c1, 2); UNPACK2(c2, 4); UNPACK2(c3, 6);
      // packed dual-pipe FP32: 64 v_pk_fma_f32
      FMAR(0); FMAR(1); FMAR(2); FMAR(3);
      FMAR(4); FMAR(5); FMAR(6); FMAR(7);
    }

    // horizontal pair-sum, then fold 64 lanes x 8 accs -> row (l>>3) sum
    // on lanes with (l&7)==0
    const float a0 = acc2[0].x + acc2[0].y, a1 = acc2[1].x + acc2[1].y;
    const float a2 = acc2[2].x + acc2[2].y, a3 = acc2[3].x + acc2[3].y;
    const float a4 = acc2[4].x + acc2[4].y, a5 = acc2[5].x + acc2[5].y;
    const float a6 = acc2[6].x + acc2[6].y, a7 = acc2[7].x + acc2[7].y;
    float t0 = (lb32 ? a4 : a0) + __shfl_xor(lb32 ? a0 : a4, 32);
    float t1 = (lb32 ? a5 : a1) + __shfl_xor(lb32 ? a1 : a5, 32);
    float t2 = (lb32 ? a6 : a2) + __shfl_xor(lb32 ? a2 : a6, 32);
    float t3 = (lb32 ? a7 : a3) + __shfl_xor(lb32 ? a3 : a7, 32);
    float s0 = (lb16 ? t2 : t0) + swz_xor16(lb16 ? t0 : t2);
    float s1 = (lb16 ? t3 : t1) + swz_xor16(lb16 ? t1 : t3);
    float r0 = (lb8 ? s1 : s0) + dpp_movf<0x128>(lb8 ? s0 : s1);
    r0 += dpp_movf<0x141>(r0);
    r0 += dpp_movf<0x1B>(r0);
    r0 += dpp_movf<0xB1>(r0);

    float x_new = fast_tanh(fmaf(win, u_t, r0));
    // pack: RN-round mantissa to 15 bits, fuse generation tag (t+1)&0xFF
    u32 packed = ((__float_as_uint(x_new) + 0x80u) & 0xFFFFFF00u)
               | ((u32)(t + 1) & 0xFFu);
    if ((l & 7) == 0) {
      u32* dst = pa ? d1 : d0;          // x_t -> buf[t&1]
      // PLAIN store: write-through L1 -> dirty in XCD0's shared L2
      // (r9-proven; r16 proved atomics force the exchange out of L2).
      asm volatile("global_store_dword %0, %1, off" :: "v"(dst), "v"(packed));
    }

    // readout y_{t-1} from this step's unpacked values (off critical path)
    if (doRead) {
      f32x2 y2 = (f32x2){0.f, 0.f};
#pragma unroll
      for (int jj = 0; jj < 8; ++jj)
        y2 = __builtin_elementwise_fma(cr2[jj], xv2[jj], y2);
      float y = y2.x + y2.y;
      YREDUCE();
      if (l == 0 && t - 1 >= WASH) out[t - 1 - WASH] = y;
    }
  }

  // final readout: x_{TT-1} (tag TT) in buf[1]; block 0 does one more exchange
  if (b == 0) {
    const u32 want = (u32)TT & 0xFFu;
    u32 guard = 0;
    for (;;) {
      POLL_ISSUE1(pS1);
      POLL_WAIT1();
      if (!TAGBAD(p)) break;
      if (++guard > SPIN_CAP) break;
    }
    *(u32x4*)(&lds_x[1][stg]) = p;
    __syncthreads();
    if (ww == 0) {
      f32x2 xv2[8];
      u32x4 c0 = *(const u32x4*)(&lds_x[1][  0 + 4 * l]);
      u32x4 c1 = *(const u32x4*)(&lds_x[1][256 + 4 * l]);
      u32x4 c2 = *(const u32x4*)(&lds_x[1][512 + 4 * l]);
      u32x4 c3 = *(const u32x4*)(&lds_x[1][768 + 4 * l]);
      UNPACK2(c0, 0); UNPACK2(c1, 2); UNPACK2(c2, 4); UNPACK2(c3, 6);
      f32x2 y2 = (f32x2){0.f, 0.f};
#pragma unroll
      for (int jj = 0; jj < 8; ++jj)
        y2 = __builtin_elementwise_fma(cr2[jj], xv2[jj], y2);
      float y = y2.x + y2.y;
      YREDUCE();
      if (l == 0) out[TT - 1 - WASH] = y;
    }
  }
}

extern "C" void kernel_launch(void* const* d_in, const int* in_sizes, int n_in,
                              void* d_out, int out_size, void* d_ws, size_t ws_size,
                              hipStream_t stream) {
  const float* u     = (const float*)d_in[0];
  const float* w_in  = (const float*)d_in[1];
  const float* w_res = (const float*)d_in[2];
  const float* w_out = (const float*)d_in[3];
  const int*   mask  = (const int*)d_in[4];
  float* out = (float*)d_out;

  // zero the block-claim counter; packed buffers rely on 0xAA poison
  // (tag byte 0xAA only ever compared against want in {1,2})
  hipMemsetAsync(d_ws, 0, 64, stream);

  esn_kernel<<<NBLK, NT, 0, stream>>>(u, w_in, w_res, w_out, mask, out,
                                      (char*)d_ws);
}

// Round 17
// 41841.052 us; speedup vs baseline: 1.4707x; 1.1143x over previous
//
#include <hip/hip_runtime.h>

// Echo-state network recurrence on MI355X (gfx950).
// Round-29: DEDICATED READER WAVE. r28 (sleep retune) hurt: in lockstep
// the sleep is inside the period's fixed point -- knob dead, sleep(2)
// restored. Remaining structural asymmetry: each step ONE compute wave
// runs the readout (~250cyc dot+serial YREDUCE) after its publish; under
// round-quantized polling that pushes its next detection up to a full
// RTT later, and the barrier makes the team inherit the max -- every
// step, since some wave is always the reader. Fix: 5th wave per block
// (NT=320). Compute waves are now UNIFORM (no doRead/cr2/final-readout).
// Block0's wave-4 polls the full state pre-barrier (concurrent with the
// quarter polls; barrier already waits for the global max), joins the
// same TT-1 barrier cadence, computes EVERY output post-barrier hidden
// under compute's longer FMA+fold phase, and handles the final output in
// an epilogue. Wave-4 of blocks 1..31 runs a barrier treadmill (keeps
// barrier counts exact without exit-UB). Placement force retained.
// Reader's y math is instruction-identical on identical data ->
// absmax 0.125 unchanged.

#define HH    1024
#define TT    50000
#define WASH  200
#define NBROLE 32   // block role b owns rows [32b, 32b+32); wave ww rows [32b+8ww, +8)
#define NBLK  512
#define NT    320   // 4 compute waves + 1 reader wave
#define SPIN_CAP (1u << 20)
#define LDSPAD 98304   // 96 KiB total LDS -> 1 block/CU (LDS pool 160 KiB)

typedef unsigned int u32;
typedef u32 u32x4 __attribute__((ext_vector_type(4)));
typedef float f32x4 __attribute__((ext_vector_type(4)));
typedef float f32x2 __attribute__((ext_vector_type(2)));

__device__ __forceinline__ float fast_tanh(float x) {
  // tanh(x) = 1 - 2/(exp2(2x*log2e)+1); safe at +/-inf.
  float e = __builtin_amdgcn_exp2f(x * 2.8853900817779268f);
  return fmaf(-2.0f, __builtin_amdgcn_rcpf(e + 1.0f), 1.0f);
}

template <int CTRL>
__device__ __forceinline__ float dpp_movf(float x) {
  return __int_as_float(__builtin_amdgcn_update_dpp(
      0, __float_as_int(x), CTRL, 0xF, 0xF, true));
}
__device__ __forceinline__ float swz_xor16(float x) {
  return __int_as_float(__builtin_amdgcn_ds_swizzle(__float_as_int(x), 0x401F));
}

#define YREDUCE()                                                         \
  { y += __shfl_xor(y, 32);                                               \
    y += swz_xor16(y);                                                    \
    y += dpp_movf<0x128>(y);   /* row_ror:8   */                          \
    y += dpp_movf<0x141>(y);   /* half mirror */                          \
    y += dpp_movf<0x1B>(y);    /* quad reverse*/                          \
    y += dpp_movf<0xB1>(y); }  /* quad xor1   */

// single 16B poll load: own quarter only (lane l -> cols 256*ww + 4l .. +3)
#define POLL_ISSUE1(bp)                                                   \
  asm volatile("global_load_dwordx4 %0, %1, off sc1" : "=v"(p) : "v"(bp))
#define POLL_WAIT1()                                                      \
  asm volatile("s_waitcnt vmcnt(0)" : "+v"(p))

// reader: 4 batched 16B loads cover all 1024 packed elements
#define RISSUE(bp)                                                                    \
  asm volatile("global_load_dwordx4 %0, %1, off sc1"             : "=v"(p0) : "v"(bp)); \
  asm volatile("global_load_dwordx4 %0, %1, off offset:1024 sc1" : "=v"(p1) : "v"(bp)); \
  asm volatile("global_load_dwordx4 %0, %1, off offset:2048 sc1" : "=v"(p2) : "v"(bp)); \
  asm volatile("global_load_dwordx4 %0, %1, off offset:3072 sc1" : "=v"(p3) : "v"(bp))
#define RWAIT()                                                           \
  asm volatile("s_waitcnt vmcnt(0)"                                       \
               : "+v"(p0), "+v"(p1), "+v"(p2), "+v"(p3))

// FULL 4-dword tag check -- load-bearing (partial-commit visibility of
// coalesced wave stores means every dword's tag matters).
#define TAGBAD(q) ((((q.x ^ want) | (q.y ^ want) | (q.z ^ want) | (q.w ^ want)) & 0xFFu))

// unpack one 16B chunk into two f32x2 value pairs (pair b2, b2+1)
#define UNPACK2(q, b2)                                                    \
  { xv2[b2+0] = (f32x2){__uint_as_float(q.x & 0xFFFFFF00u),               \
                        __uint_as_float(q.y & 0xFFFFFF00u)};              \
    xv2[b2+1] = (f32x2){__uint_as_float(q.z & 0xFFFFFF00u),               \
                        __uint_as_float(q.w & 0xFFFFFF00u)}; }

// --- named weight registers: row r, pairs 0..7 (cols 256*(p>>1)+4l+{2(p&1),+1})
#define DECLW(r) f32x2 W##r##0, W##r##1, W##r##2, W##r##3,                \
                      W##r##4, W##r##5, W##r##6, W##r##7

#define LOADW(r) do {                                                     \
  const float* wp = w_res + (size_t)(32 * b + 8 * ww + r) * HH + 4 * l;   \
  f32x4 va = *(const f32x4*)(wp);                                         \
  f32x4 vb = *(const f32x4*)(wp + 256);                                   \
  f32x4 vc = *(const f32x4*)(wp + 512);                                   \
  f32x4 vd = *(const f32x4*)(wp + 768);                                   \
  W##r##0 = (f32x2){va.x, va.y}; W##r##1 = (f32x2){va.z, va.w};           \
  W##r##2 = (f32x2){vb.x, vb.y}; W##r##3 = (f32x2){vb.z, vb.w};           \
  W##r##4 = (f32x2){vc.x, vc.y}; W##r##5 = (f32x2){vc.z, vc.w};           \
  W##r##6 = (f32x2){vd.x, vd.y}; W##r##7 = (f32x2){vd.z, vd.w};           \
} while (0)

// jj ascending per accumulator -> identical summation order to r13-r28
#define FMAR(r) do {                                                      \
  acc2[r] = __builtin_elementwise_fma(W##r##0, xv2[0], acc2[r]);          \
  acc2[r] = __builtin_elementwise_fma(W##r##1, xv2[1], acc2[r]);          \
  acc2[r] = __builtin_elementwise_fma(W##r##2, xv2[2], acc2[r]);          \
  acc2[r] = __builtin_elementwise_fma(W##r##3, xv2[3], acc2[r]);          \
  acc2[r] = __builtin_elementwise_fma(W##r##4, xv2[4], acc2[r]);          \
  acc2[r] = __builtin_elementwise_fma(W##r##5, xv2[5], acc2[r]);          \
  acc2[r] = __builtin_elementwise_fma(W##r##6, xv2[6], acc2[r]);          \
  acc2[r] = __builtin_elementwise_fma(W##r##7, xv2[7], acc2[r]);          \
} while (0)

__global__ __launch_bounds__(NT, 1) void esn_kernel(
    const float* __restrict__ u,
    const float* __restrict__ w_in,
    const float* __restrict__ w_res,
    const float* __restrict__ w_out,
    const int*   __restrict__ mask,
    float*       __restrict__ out,
    char*        __restrict__ ws)
{
  const int tid = threadIdx.x;
  const int l  = tid & 63;     // lane within wave
  const int ww = tid >> 6;     // wave id within block (0..4); 4 = reader

  // --- team formation: XCD 0 only, first 32 claimant BLOCKS persist ---
  u32 xcc;
  asm("s_getreg_b32 %0, hwreg(HW_REG_XCC_ID)" : "=s"(xcc));
  if (xcc != 0) return;        // uniform per block (block lives on one CU)

  // PLACEMENT FORCE (r22-proven): 96 KiB static LDS -> 1 block/CU ->
  // the 32 claim winners sit on 32 distinct CUs.
  __shared__ __align__(16) char lds_all[LDSPAD];
  float* lds_c = (float*)lds_all;                        // 4 KB coeffs
  u32 (*lds_x)[HH] = (u32 (*)[HH])(lds_all + 4096);      // 2x4 KB state
  int* slot_p = (int*)(lds_all + 4096 + 8192);

  if (tid == 0) *slot_p = atomicAdd((int*)ws, 1);  // ws[0..63] zeroed each launch
  // init readout coeffs while the claim settles
  for (int h = tid; h < HH; h += NT) lds_c[mask[h]] = w_out[h];
  __syncthreads();
  const int b = *slot_p;
  if (b >= NBROLE) return;

  u32* xb0 = (u32*)(ws + 4096);        // parity-0 packed buffer (4 KB)
  u32* xb1 = xb0 + HH;                 // parity-1 packed buffer (4 KB)

  // ================= READER WAVE (ww == 4) =================
  if (ww == 4) {
    if (b != 0) {
      // barrier treadmill: keep this block's per-workgroup barrier count
      // aligned with its 4 compute waves (TT-1 barriers), zero work.
      for (int t = 1; t < TT; ++t) __syncthreads();
      return;
    }
    // active reader: computes EVERY output, off the compute critical path
    f32x2 cr2[8];
#pragma unroll
    for (int k = 0; k < 4; ++k) {
      f32x4 v = *(const f32x4*)(lds_c + 256 * k + 4 * l);
      cr2[2*k+0] = (f32x2){v.x, v.y};
      cr2[2*k+1] = (f32x2){v.z, v.w};
    }
    const u32* rA0 = xb0 + 4 * l;
    const u32* rA1 = xb1 + 4 * l;
    u32x4 p0, p1, p2, p3;
    int dead = 0;
    for (int t = 1; t < TT; ++t) {
      const bool work = (t - 1 >= WASH) && !dead;
      if (work) {
        // poll full state x_{t-1} (tag t) -- concurrent with the compute
        // waves' quarter polls; the barrier waits for the global max
        // either way, so this adds no latency.
        __builtin_amdgcn_s_sleep(2);
        const u32* src = ((t - 1) & 1) ? rA1 : rA0;
        const u32 want = (u32)t & 0xFFu;
        u32 guard = 0;
        for (;;) {
          RISSUE(src);
          RWAIT();
          if (!(TAGBAD(p0) | TAGBAD(p1) | TAGBAD(p2) | TAGBAD(p3))) break;
          if (++guard > SPIN_CAP) { dead = 1; break; }
        }
      }
      __syncthreads();                 // cadence: one barrier per t, 1..TT-1
      if (work) {
        // y compute hidden under compute waves' LDS-read+FMA+fold phase
        f32x2 xv2[8];
        UNPACK2(p0, 0); UNPACK2(p1, 2); UNPACK2(p2, 4); UNPACK2(p3, 6);
        f32x2 y2 = (f32x2){0.f, 0.f};
#pragma unroll
        for (int jj = 0; jj < 8; ++jj)
          y2 = __builtin_elementwise_fma(cr2[jj], xv2[jj], y2);
        float y = y2.x + y2.y;
        YREDUCE();
        if (l == 0) out[t - 1 - WASH] = y;
      }
    }
    // final output: x_{TT-1} (tag TT) in buf[(TT-1)&1] = buf[1]
    if (!dead) {
      const u32 want = (u32)TT & 0xFFu;
      u32 guard = 0;
      for (;;) {
        RISSUE(rA1);
        RWAIT();
        if (!(TAGBAD(p0) | TAGBAD(p1) | TAGBAD(p2) | TAGBAD(p3))) break;
        if (++guard > SPIN_CAP) break;
      }
      f32x2 xv2[8];
      UNPACK2(p0, 0); UNPACK2(p1, 2); UNPACK2(p2, 4); UNPACK2(p3, 6);
      f32x2 y2 = (f32x2){0.f, 0.f};
#pragma unroll
      for (int jj = 0; jj < 8; ++jj)
        y2 = __builtin_elementwise_fma(cr2[jj], xv2[jj], y2);
      float y = y2.x + y2.y;
      YREDUCE();
      if (l == 0) out[TT - 1 - WASH] = y;
    }
    return;
  }

  // ================= COMPUTE WAVES (ww < 4) =================
  // weights: 8 rows x 8 col-pairs per lane (rows 32b+8ww .. +8)
  DECLW(0); DECLW(1); DECLW(2); DECLW(3);
  DECLW(4); DECLW(5); DECLW(6); DECLW(7);
  LOADW(0); LOADW(1); LOADW(2); LOADW(3);
  LOADW(4); LOADW(5); LOADW(6); LOADW(7);

  const float win = w_in[32 * b + 8 * ww + (l >> 3)];

  // own-quarter poll pointers: wave ww covers cols [256ww, 256ww+256)
  const u32* pS0 = xb0 + 256 * ww + 4 * l;
  const u32* pS1 = xb1 + 256 * ww + 4 * l;
  // publish pointers: lane (l&7)==0 stores row 32b+8ww+(l>>3)
  const int drow = 32 * b + 8 * ww + (l >> 3);
  u32* d0 = xb0 + drow;
  u32* d1 = xb1 + drow;
  // LDS staging address (own quarter)
  const int stg = 256 * ww + 4 * l;

  u32x4 p;
  const int lb32 = l & 32, lb16 = l & 16, lb8 = l & 8;
  int dead = 0;

  for (int t = 0; t < TT; ++t) {
    const int pa = t & 1;
    const float u_t = u[t];
    f32x2 acc2[8];
#pragma unroll
    for (int i = 0; i < 8; ++i) acc2[i] = (f32x2){0.f, 0.f};
    f32x2 xv2[8];

    if (t > 0) {
      const int h = pa ^ 1;            // source parity = (t-1)&1
      if (!dead) {
        // delayed first poll (r22 value): sleep(2)=128cyc hidden slack
        __builtin_amdgcn_s_sleep(2);
        const u32* src = h ? pS1 : pS0;
        const u32 want = (u32)t & 0xFFu;   // generation of x_{t-1}
        u32 guard = 0;
        for (;;) {
          POLL_ISSUE1(src);
          POLL_WAIT1();
          if (!TAGBAD(p)) break;
          if (++guard > SPIN_CAP) { dead = 1; break; }
        }
      }
      // stage own quarter to LDS; barrier; read full state from LDS
      *(u32x4*)(&lds_x[h][stg]) = p;
      __syncthreads();
      u32x4 c0 = *(const u32x4*)(&lds_x[h][  0 + 4 * l]);
      u32x4 c1 = *(const u32x4*)(&lds_x[h][256 + 4 * l]);
      u32x4 c2 = *(const u32x4*)(&lds_x[h][512 + 4 * l]);
      u32x4 c3 = *(const u32x4*)(&lds_x[h][768 + 4 * l]);
      UNPACK2(c0, 0); UNPACK2(c1, 2); UNPACK2(c2, 4); UNPACK2(c3, 6);
      // packed dual-pipe FP32: 64 v_pk_fma_f32
      FMAR(0); FMAR(1); FMAR(2); FMAR(3);
      FMAR(4); FMAR(5); FMAR(6); FMAR(7);
    }

    // horizontal pair-sum, then fold 64 lanes x 8 accs -> row (l>>3) sum
    // on lanes with (l&7)==0
    const float a0 = acc2[0].x + acc2[0].y, a1 = acc2[1].x + acc2[1].y;
    const float a2 = acc2[2].x + acc2[2].y, a3 = acc2[3].x + acc2[3].y;
    const float a4 = acc2[4].x + acc2[4].y, a5 = acc2[5].x + acc2[5].y;
    const float a6 = acc2[6].x + acc2[6].y, a7 = acc2[7].x + acc2[7].y;
    float t0 = (lb32 ? a4 : a0) + __shfl_xor(lb32 ? a0 : a4, 32);
    float t1 = (lb32 ? a5 : a1) + __shfl_xor(lb32 ? a1 : a5, 32);
    float t2 = (lb32 ? a6 : a2) + __shfl_xor(lb32 ? a2 : a6, 32);
    float t3 = (lb32 ? a7 : a3) + __shfl_xor(lb32 ? a3 : a7, 32);
    float s0 = (lb16 ? t2 : t0) + swz_xor16(lb16 ? t0 : t2);
    float s1 = (lb16 ? t3 : t1) + swz_xor16(lb16 ? t1 : t3);
    float r0 = (lb8 ? s1 : s0) + dpp_movf<0x128>(lb8 ? s0 : s1);
    r0 += dpp_movf<0x141>(r0);
    r0 += dpp_movf<0x1B>(r0);
    r0 += dpp_movf<0xB1>(r0);

    float x_new = fast_tanh(fmaf(win, u_t, r0));
    // pack: RN-round mantissa to 15 bits, fuse generation tag (t+1)&0xFF
    u32 packed = ((__float_as_uint(x_new) + 0x80u) & 0xFFFFFF00u)
               | ((u32)(t + 1) & 0xFFu);
    if ((l & 7) == 0) {
      u32* dst = pa ? d1 : d0;          // x_t -> buf[t&1]
      // PLAIN store: write-through L1 -> dirty in XCD0's shared L2
      // (r9-proven; r16 proved atomics force the exchange out of L2).
      asm volatile("global_store_dword %0, %1, off" :: "v"(dst), "v"(packed));
    }
  }
}

extern "C" void kernel_launch(void* const* d_in, const int* in_sizes, int n_in,
                              void* d_out, int out_size, void* d_ws, size_t ws_size,
                              hipStream_t stream) {
  const float* u     = (const float*)d_in[0];
  const float* w_in  = (const float*)d_in[1];
  const float* w_res = (const float*)d_in[2];
  const float* w_out = (const float*)d_in[3];
  const int*   mask  = (const int*)d_in[4];
  float* out = (float*)d_out;

  // zero the block-claim counter; packed buffers rely on 0xAA poison
  // (tag byte 0xAA only ever compared against want in {1,2})
  hipMemsetAsync(d_ws, 0, 64, stream);

  esn_kernel<<<NBLK, NT, 0, stream>>>(u, w_in, w_res, w_out, mask, out,
                                      (char*)d_ws);
}